// Round 1
// baseline (129.070 us; speedup 1.0000x reference)
//
#include <hip/hip_runtime.h>

#define LOG2E 1.44269504088896340736f

// a * t * sigmoid(c * t), with cl = c * log2(e) prefolded
__device__ __forceinline__ float moth1(float t, float a, float cl) {
    float e = __builtin_amdgcn_exp2f(-cl * t);        // exp(-c*t)
    float s = __builtin_amdgcn_rcpf(1.0f + e);        // sigmoid(c*t)
    return a * t * s;
}

struct Weights {
    float w1[16];   // W1 [2,8] row-major
    float bb1[8], aa1[8], cl1[8];
    float w2[32];   // W2 [8,4] row-major
    float bb2[4], aa2[4], cl2[4];
    float w3[4];    // W3 [4,1]
    float bb3;
};

__device__ __forceinline__ float row_compute(float x0, float x1, const Weights& W) {
    float h[8];
#pragma unroll
    for (int j = 0; j < 8; ++j) {
        float t = fmaf(x0, W.w1[j], fmaf(x1, W.w1[8 + j], W.bb1[j]));
        h[j] = moth1(t, W.aa1[j], W.cl1[j]);
    }
    float o = W.bb3;
#pragma unroll
    for (int k = 0; k < 4; ++k) {
        float t = W.bb2[k];
#pragma unroll
        for (int j = 0; j < 8; ++j) t = fmaf(h[j], W.w2[j * 4 + k], t);
        float g = moth1(t, W.aa2[k], W.cl2[k]);
        o = fmaf(g, W.w3[k], o);
    }
    return o;
}

__global__ __launch_bounds__(256) void PlaygroundModel_66365834658304_kernel(
    const float* __restrict__ x,
    const float* __restrict__ W1, const float* __restrict__ b1,
    const float* __restrict__ a1, const float* __restrict__ c1,
    const float* __restrict__ W2, const float* __restrict__ b2,
    const float* __restrict__ a2, const float* __restrict__ c2,
    const float* __restrict__ W3, const float* __restrict__ b3,
    float* __restrict__ out, int rows)
{
    // Load all weights. Addresses are wave-uniform kernel-arg expressions ->
    // compiler emits scalar s_load broadcasts; cached in L1/L2 after block 0.
    Weights W;
#pragma unroll
    for (int i = 0; i < 16; ++i) W.w1[i] = W1[i];
#pragma unroll
    for (int i = 0; i < 8; ++i) {
        W.bb1[i] = b1[i];
        W.aa1[i] = a1[i];
        W.cl1[i] = c1[i] * LOG2E;   // fold log2(e) into c once
    }
#pragma unroll
    for (int i = 0; i < 32; ++i) W.w2[i] = W2[i];
#pragma unroll
    for (int i = 0; i < 4; ++i) {
        W.bb2[i] = b2[i];
        W.aa2[i] = a2[i];
        W.cl2[i] = c2[i] * LOG2E;
        W.w3[i]  = W3[i];
    }
    W.bb3 = b3[0];

    int tid = blockIdx.x * blockDim.x + threadIdx.x;
    long long base = (long long)tid * 4;   // first row of this thread's 4
    if (base >= rows) return;

    if (base + 3 < rows) {
        // fast path: 2x float4 load (4 rows of x), 1x float4 store
        const float4* x4 = (const float4*)x;
        float4 p0 = x4[(size_t)tid * 2 + 0];   // rows base+0, base+1
        float4 p1 = x4[(size_t)tid * 2 + 1];   // rows base+2, base+3
        float4 o;
        o.x = row_compute(p0.x, p0.y, W);
        o.y = row_compute(p0.z, p0.w, W);
        o.z = row_compute(p1.x, p1.y, W);
        o.w = row_compute(p1.z, p1.w, W);
        ((float4*)out)[tid] = o;
    } else {
        // tail (not hit for B = 8388608, kept for safety)
        for (long long r = base; r < rows; ++r) {
            float x0 = x[r * 2 + 0];
            float x1 = x[r * 2 + 1];
            out[r] = row_compute(x0, x1, W);
        }
    }
}

extern "C" void kernel_launch(void* const* d_in, const int* in_sizes, int n_in,
                              void* d_out, int out_size, void* d_ws, size_t ws_size,
                              hipStream_t stream) {
    const float* x  = (const float*)d_in[0];
    const float* W1 = (const float*)d_in[1];
    const float* b1 = (const float*)d_in[2];
    const float* a1 = (const float*)d_in[3];
    const float* c1 = (const float*)d_in[4];
    const float* W2 = (const float*)d_in[5];
    const float* b2 = (const float*)d_in[6];
    const float* a2 = (const float*)d_in[7];
    const float* c2 = (const float*)d_in[8];
    const float* W3 = (const float*)d_in[9];
    const float* b3 = (const float*)d_in[10];
    float* out = (float*)d_out;

    int rows  = in_sizes[0] / 2;           // [B,2] -> B
    int rows4 = (rows + 3) / 4;            // threads, 4 rows each
    int block = 256;
    int grid  = (rows4 + block - 1) / block;

    PlaygroundModel_66365834658304_kernel<<<grid, block, 0, stream>>>(
        x, W1, b1, a1, c1, W2, b2, a2, c2, W3, b3, out, rows);
}

// Round 2
// 128.466 us; speedup vs baseline: 1.0047x; 1.0047x over previous
//
#include <hip/hip_runtime.h>

#define NLOG2E -1.44269504088896340736f

// out = a*t*sigmoid(c*t) decomposed as t*rcp(1+exp2(-c*log2e*t)), with the
// per-feature 'a' folded into the NEXT layer's weights (uniform-time math).

__global__ __launch_bounds__(256, 2) void PlaygroundModel_66365834658304_kernel(
    const float* __restrict__ x,
    const float* __restrict__ W1, const float* __restrict__ b1,
    const float* __restrict__ a1, const float* __restrict__ c1,
    const float* __restrict__ W2, const float* __restrict__ b2,
    const float* __restrict__ a2, const float* __restrict__ c2,
    const float* __restrict__ W3, const float* __restrict__ b3,
    float* __restrict__ out, int rows)
{
    int tid = blockIdx.x * blockDim.x + threadIdx.x;
    long long base = (long long)tid * 4;
    if (base >= rows) return;

    // ---- uniform weight prep (scalar loads -> SGPRs; 77 live values) ----
    float w1a[8], w1b[8], bb1[8], ncl1[8];
#pragma unroll
    for (int j = 0; j < 8; ++j) {
        w1a[j]  = W1[j];        // row for x0
        w1b[j]  = W1[8 + j];    // row for x1
        bb1[j]  = b1[j];
        ncl1[j] = c1[j] * NLOG2E;
    }
    float w2f[32];              // a1 folded in: w2f[j][k] = a1[j]*W2[j][k]
#pragma unroll
    for (int j = 0; j < 8; ++j) {
        float a = a1[j];
#pragma unroll
        for (int k = 0; k < 4; ++k) w2f[j * 4 + k] = a * W2[j * 4 + k];
    }
    float bb2[4], ncl2[4], aw[4];
#pragma unroll
    for (int k = 0; k < 4; ++k) {
        bb2[k]  = b2[k];
        ncl2[k] = c2[k] * NLOG2E;
        aw[k]   = a2[k] * W3[k];   // a2 folded into W3
    }
    float bb3 = b3[0];

    if (base + 3 < rows) {
        const float4* x4 = (const float4*)x;
        float4 p0 = x4[(size_t)tid * 2 + 0];
        float4 p1 = x4[(size_t)tid * 2 + 1];
        float xs0[4] = {p0.x, p0.z, p1.x, p1.z};
        float xs1[4] = {p0.y, p0.w, p1.y, p1.w};
        float r[4];
#pragma unroll
        for (int r4 = 0; r4 < 4; ++r4) {
            float x0 = xs0[r4], x1 = xs1[r4];
            float h[8];
#pragma unroll
            for (int j = 0; j < 8; ++j) {
                float t = fmaf(x0, w1a[j], fmaf(x1, w1b[j], bb1[j]));
                float s = __builtin_amdgcn_rcpf(
                              1.0f + __builtin_amdgcn_exp2f(ncl1[j] * t));
                h[j] = t * s;   // a1 already folded into w2f
            }
            float o = bb3;
#pragma unroll
            for (int k = 0; k < 4; ++k) {
                float t = bb2[k];
#pragma unroll
                for (int j = 0; j < 8; ++j) t = fmaf(h[j], w2f[j * 4 + k], t);
                float s = __builtin_amdgcn_rcpf(
                              1.0f + __builtin_amdgcn_exp2f(ncl2[k] * t));
                o = fmaf(t * s, aw[k], o);   // a2 already folded into aw
            }
            r[r4] = o;
        }
        float4 ov = make_float4(r[0], r[1], r[2], r[3]);
        ((float4*)out)[tid] = ov;
    } else {
        // tail (not hit for B = 8388608)
        for (long long rr = base; rr < rows; ++rr) {
            float x0 = x[rr * 2 + 0], x1 = x[rr * 2 + 1];
            float h[8];
#pragma unroll
            for (int j = 0; j < 8; ++j) {
                float t = fmaf(x0, w1a[j], fmaf(x1, w1b[j], bb1[j]));
                float s = __builtin_amdgcn_rcpf(
                              1.0f + __builtin_amdgcn_exp2f(ncl1[j] * t));
                h[j] = t * s;
            }
            float o = bb3;
#pragma unroll
            for (int k = 0; k < 4; ++k) {
                float t = bb2[k];
#pragma unroll
                for (int j = 0; j < 8; ++j) t = fmaf(h[j], w2f[j * 4 + k], t);
                float s = __builtin_amdgcn_rcpf(
                              1.0f + __builtin_amdgcn_exp2f(ncl2[k] * t));
                o = fmaf(t * s, aw[k], o);
            }
            out[rr] = o;
        }
    }
}

extern "C" void kernel_launch(void* const* d_in, const int* in_sizes, int n_in,
                              void* d_out, int out_size, void* d_ws, size_t ws_size,
                              hipStream_t stream) {
    const float* x  = (const float*)d_in[0];
    const float* W1 = (const float*)d_in[1];
    const float* b1 = (const float*)d_in[2];
    const float* a1 = (const float*)d_in[3];
    const float* c1 = (const float*)d_in[4];
    const float* W2 = (const float*)d_in[5];
    const float* b2 = (const float*)d_in[6];
    const float* a2 = (const float*)d_in[7];
    const float* c2 = (const float*)d_in[8];
    const float* W3 = (const float*)d_in[9];
    const float* b3 = (const float*)d_in[10];
    float* out = (float*)d_out;

    int rows  = in_sizes[0] / 2;
    int rows4 = (rows + 3) / 4;
    int block = 256;
    int grid  = (rows4 + block - 1) / block;

    PlaygroundModel_66365834658304_kernel<<<grid, block, 0, stream>>>(
        x, W1, b1, a1, c1, W2, b2, a2, c2, W3, b3, out, rows);
}